// Round 4
// baseline (112.003 us; speedup 1.0000x reference)
//
#include <hip/hip_runtime.h>
#include <math.h>

// PureCartesianE3Conv on MI355X — round 12.
// r10: cg grid.sync ~40us each on MI355X -> never again.
// r11: atomic-free scatter was right, but redundant per-block scans in k_mid
//      (196x 40KB nodecnt reload + stride-196 blkhist walks) cost ~15us.
// r12: same machinery, scans done ONCE in a tiny k_scan (2 blocks):
//   memset(nodecnt)
//   k_front  = pairtab | htab | count  (rank capture, blkhist in [b][p] layout)
//   k_scan   = block0: node prefix -> row_off; block1: pair totals + padded
//              bases + 2D blkbase prefix (coalesced) + b2p + slot padding
//   k_scatter= PURE (no atomics, no re-gather): slot = blkbase[bid][p] + rp,
//              s2v = row_off[d] + rn; geometry + v4/geo writes
//   k_edge, k_node unchanged from r9.

#define NPAIR 100
#define SCHUNK 512
#define TS 8192
#define NB_TAB (TS / 64)
#define LSCALE (8192.0f / 7.0f)
#define LSTEP  (7.0f / 8192.0f)
#define MAXN_LDS 10240   // problem fixes N_NODES = 10000

__device__ __forceinline__ float silu_acc(float x) {
    return x / (1.0f + expf(-x));   // precise: setup path only
}

// ================= phase device functions =================

__device__ void d_pairtab(int p, int tid, float* lds,
    const float* emb_table, const float* Wa1, const float* ba1,
    const float* Wa2, const float* ba2,
    const float* Wf3, const float* bf3,
    float* M, float* bM)
{
    int pa = p / 10, pb = p % 10;
    float* sh = lds;             // 128
    float* sP = lds + 128;       // 8
    if (tid < 128) {
        int row = (tid < 64) ? pa : pb;
        int j = tid & 63;
        float a = ba1[j];
#pragma unroll
        for (int k = 0; k < 16; ++k) a = fmaf(emb_table[row * 16 + k], Wa1[k * 64 + j], a);
        sh[tid] = silu_acc(a);
    }
    __syncthreads();
    if (tid < 8) {
        float aa = ba2[tid], ab = ba2[tid];
        for (int j = 0; j < 64; ++j) {
            aa = fmaf(sh[j], Wa2[j * 8 + tid], aa);
            ab = fmaf(sh[64 + j], Wa2[j * 8 + tid], ab);
        }
        sP[tid] = aa * ab;
    }
    __syncthreads();
    for (int base = tid; base < 3072; base += 256) {
        int h = base / 48;
        int j = base - h * 48;
        const float* wr = Wf3 + h * 1536 + (j >> 4) * 128 + (j & 15);
        float a = 0.0f;
#pragma unroll
        for (int c = 0; c < 8; ++c) a = fmaf(sP[c], wr[c * 16], a);
        M[p * 3072 + base] = a;
    }
    if (tid < 48) {
        const float* br = bf3 + (tid >> 4) * 128 + (tid & 15);
        float a = 0.0f;
#pragma unroll
        for (int c = 0; c < 8; ++c) a = fmaf(sP[c], br[c * 16], a);
        bM[p * 48 + tid] = a;
    }
}

__device__ void d_htab(int blk, int tid, float* lds,
    const float* Wf1, const float* bf1, const float* Wf2, const float* bf2,
    float* Htab)
{
    int w = __builtin_amdgcn_readfirstlane(tid >> 6);
    int lane = tid & 63;
    int s = blk * 64 + lane;
    float len = (float)s * LSTEP;
    float ek[8];
#pragma unroll
    for (int k = 0; k < 8; ++k) {
        float d = fmaf(len, 1.8f, -(float)(k + 1));
        ek[k] = expf(-d * d) * 2.5253813613805388f;   // sqrt(8)/1.12
    }
    float t[16];
    {
        const float* bq = bf1 + w * 16;
#pragma unroll
        for (int j = 0; j < 16; ++j) t[j] = bq[j];
#pragma unroll
        for (int k = 0; k < 8; ++k) {
            float e8 = ek[k];
            const float* wr = Wf1 + k * 64 + w * 16;
#pragma unroll
            for (int j = 0; j < 16; ++j) t[j] = fmaf(e8, wr[j], t[j]);
        }
#pragma unroll
        for (int j = 0; j < 16; ++j) lds[(w * 16 + j) * 64 + lane] = silu_acc(t[j]);
    }
    __syncthreads();
    float h2[16];
    {
        const float* bq = bf2 + w * 16;
#pragma unroll
        for (int j = 0; j < 16; ++j) h2[j] = bq[j];
    }
#pragma unroll 8
    for (int k = 0; k < 64; ++k) {
        float hk = lds[k * 64 + lane];
        const float* wr = Wf2 + k * 64 + w * 16;
#pragma unroll
        for (int j = 0; j < 16; ++j) h2[j] = fmaf(hk, wr[j], h2[j]);
    }
    float* tp = Htab + (size_t)s * 64 + w * 16;
#pragma unroll
    for (int j = 0; j < 16; ++j) tp[j] = silu_acc(h2[j]);
}

// ================= front kernel: pairtab | htab | count =================

__global__ __launch_bounds__(256) void k_front(
    int E,
    const int* __restrict__ esrc, const int* __restrict__ edst,
    const int* __restrict__ Aarr,
    int* __restrict__ nodecnt, int* __restrict__ blkhist,
    int* __restrict__ info_r, unsigned short* __restrict__ info_p,
    const float* __restrict__ emb_table, const float* __restrict__ Wa1,
    const float* __restrict__ ba1, const float* __restrict__ Wa2,
    const float* __restrict__ ba2,
    const float* __restrict__ Wf1, const float* __restrict__ bf1,
    const float* __restrict__ Wf2, const float* __restrict__ bf2,
    const float* __restrict__ Wf3, const float* __restrict__ bf3,
    float* __restrict__ M, float* __restrict__ bM, float* __restrict__ Htab)
{
    __shared__ __align__(16) char sm[16384];
    int bid = blockIdx.x;
    int tid = threadIdx.x;

    if (bid < NPAIR) {
        d_pairtab(bid, tid, (float*)sm, emb_table, Wa1, ba1, Wa2, ba2, Wf3, bf3, M, bM);
        return;
    }
    bid -= NPAIR;
    if (bid < NB_TAB) {
        d_htab(bid, tid, (float*)sm, Wf1, bf1, Wf2, bf2, Htab);
        return;
    }
    bid -= NB_TAB;

    // ---- count: rank capture + per-block pair histogram ([b][p] layout) ----
    int* hist = (int*)sm;
    if (tid < NPAIR) hist[tid] = 0;
    __syncthreads();
    int base = bid * SCHUNK;
#pragma unroll
    for (int i = 0; i < SCHUNK / 256; ++i) {
        int e = base + tid + i * 256;
        if (e < E) {
            int d = edst[e];
            int s = esrc[e];
            int rn = atomicAdd(&nodecnt[d], 1);          // global rank within node
            int p = Aarr[s] * 10 + Aarr[d];
            int rp = atomicAdd(&hist[p], 1);             // rank within (block, pair)
            info_r[e] = rn;
            info_p[e] = (unsigned short)((rp << 7) | p); // rp<512 (9b), p<100 (7b)
        }
    }
    __syncthreads();
    if (tid < NPAIR) blkhist[bid * NPAIR + tid] = hist[tid];
}

// ================= scan kernel: 2 blocks, all prefix work once =================

__global__ __launch_bounds__(256) void k_scan(
    int nhblk, int N, int maxblk,
    const int* __restrict__ nodecnt, const int* __restrict__ blkhist,
    int* __restrict__ row_off, int* __restrict__ blkbase,
    int* __restrict__ b2p, int* __restrict__ einv, float* __restrict__ geo)
{
    int tid = threadIdx.x;
    if (blockIdx.x == 0) {
        // ---- node prefix scan -> row_off ----
        __shared__ int roff[MAXN_LDS];
        __shared__ int sscan[256];
        for (int i = tid; i < N; i += 256) roff[i] = nodecnt[i];
        __syncthreads();
        int CH = (N + 255) / 256;
        int start = tid * CH, end = min(start + CH, N);
        int s = 0;
        for (int i = start; i < end; ++i) s += roff[i];
        sscan[tid] = s;
        __syncthreads();
        for (int o = 1; o < 256; o <<= 1) {
            int y = (tid >= o) ? sscan[tid - o] : 0;
            __syncthreads();
            sscan[tid] += y;
            __syncthreads();
        }
        int run = sscan[tid] - s;
        for (int i = start; i < end; ++i) { int c = roff[i]; row_off[i] = run; run += c; }
        if (tid == 255) row_off[N] = sscan[255];
    } else {
        // ---- pair totals, padded bases, 2D blkbase prefix, b2p, padding ----
        __shared__ int tot[NPAIR];
        __shared__ int spb[NPAIR + 1];
        __shared__ int susd;
        if (tid < NPAIR) {
            int t = 0;
            for (int b = 0; b < nhblk; ++b) t += blkhist[b * NPAIR + tid];
            tot[tid] = t;
        }
        __syncthreads();
        if (tid == 0) {
            int runb = 0;
            for (int p = 0; p < NPAIR; ++p) {
                spb[p] = runb * 64;
                runb += (tot[p] + 63) >> 6;
            }
            spb[NPAIR] = runb * 64;
            susd = runb;
        }
        __syncthreads();
        if (tid < NPAIR) {
            int run = spb[tid];
            for (int b = 0; b < nhblk; ++b) {
                blkbase[b * NPAIR + tid] = run;
                run += blkhist[b * NPAIR + tid];
            }
        }
        for (int b = tid; b < maxblk; b += 256) b2p[b] = -1;
        __syncthreads();
        if (tid < NPAIR) {
            int ob = spb[tid] >> 6;
            int oe = spb[tid + 1] >> 6;
            for (int b = ob; b < oe; ++b) b2p[b] = tid;
            for (int q = spb[tid] + tot[tid]; q < spb[tid + 1]; ++q) {
                einv[q] = -1;
                geo[q] = 0.0f;
            }
        }
        (void)susd;
    }
}

// ================= scatter: pure function, no atomics =================

__global__ __launch_bounds__(256) void k_scatter(
    int E,
    const int* __restrict__ esrc, const int* __restrict__ edst,
    const float* __restrict__ pos, const float* __restrict__ edge_shifts,
    const float* __restrict__ cell, const int* __restrict__ batch,
    const int* __restrict__ row_off, const int* __restrict__ blkbase,
    const int* __restrict__ info_r, const unsigned short* __restrict__ info_p,
    int* __restrict__ einv, float* __restrict__ geo, float* __restrict__ v4)
{
    __shared__ int sbase[NPAIR];
    int tid = threadIdx.x;
    int bid = blockIdx.x;
    if (tid < NPAIR) sbase[tid] = blkbase[bid * NPAIR + tid];
    __syncthreads();
    int base = bid * SCHUNK;
#pragma unroll
    for (int i = 0; i < SCHUNK / 256; ++i) {
        int e = base + tid + i * 256;
        if (e < E) {
            int d = edst[e];
            int src = esrc[e];
            int rn = info_r[e];
            int ip = (int)info_p[e];
            int p = ip & 127;
            int rp = ip >> 7;
            int slot = sbase[p] + rp;
            int s2v = row_off[d] + rn;
            einv[slot] = s2v;
            int b = batch[src];
            float s0 = edge_shifts[e * 3 + 0];
            float s1 = edge_shifts[e * 3 + 1];
            float s2 = edge_shifts[e * 3 + 2];
            const float* cm = cell + b * 9;
            float ev0 = pos[d * 3 + 0] - pos[src * 3 + 0] + s0 * cm[0] + s1 * cm[3] + s2 * cm[6];
            float ev1 = pos[d * 3 + 1] - pos[src * 3 + 1] + s0 * cm[1] + s1 * cm[4] + s2 * cm[7];
            float ev2 = pos[d * 3 + 2] - pos[src * 3 + 2] + s0 * cm[2] + s1 * cm[5] + s2 * cm[8];
            float len = sqrtf(ev0 * ev0 + ev1 * ev1 + ev2 * ev2);
            float inv = 1.0f / (len + 1e-12f);
            reinterpret_cast<float4*>(v4)[s2v] =
                make_float4(ev0 * inv, ev1 * inv, ev2 * inv, len);
            geo[slot] = len * LSCALE;
        }
    }
}

// ================= fused per-edge kernel =================

__global__ __launch_bounds__(256, 6) void k_edge(
    const int* __restrict__ b2p, const int* __restrict__ einv,
    const float* __restrict__ geo, const float* __restrict__ Htab,
    const float* __restrict__ M, const float* __restrict__ bM,
    float* __restrict__ gout)
{
    __shared__ float hbuf[64 * 64];  // 16 KB, [k][lane]
    int p = b2p[blockIdx.x];
    if (p < 0) return;
    p = __builtin_amdgcn_readfirstlane(p);
    int tid = threadIdx.x;
    int w = __builtin_amdgcn_readfirstlane(tid >> 6);  // wave id 0..3, SGPR
    int lane = tid & 63;
    int slot = blockIdx.x * 64 + lane;
    int ci = einv[slot];
    bool act = ci >= 0;

    // ---- fill hbuf via table gather + linear interp (wave w fills k in [w*16,+16)) ----
    float u = geo[slot];                       // len * LSCALE (0 for padding)
    int i0 = (int)u;
    i0 = min(max(i0, 0), TS - 2);
    float frac = u - (float)i0;
    const float4* r0 = reinterpret_cast<const float4*>(Htab + (size_t)i0 * 64 + w * 16);
    float4 ta[4], tb[4];
#pragma unroll
    for (int i = 0; i < 4; ++i) { ta[i] = r0[i]; tb[i] = r0[i + 16]; }  // +16 f4 = next row
    float* hb = hbuf + (w * 16) * 64 + lane;
#pragma unroll
    for (int i = 0; i < 4; ++i) {
        hb[(4 * i + 0) * 64] = fmaf(frac, tb[i].x - ta[i].x, ta[i].x);
        hb[(4 * i + 1) * 64] = fmaf(frac, tb[i].y - ta[i].y, ta[i].y);
        hb[(4 * i + 2) * 64] = fmaf(frac, tb[i].z - ta[i].z, ta[i].z);
        hb[(4 * i + 3) * 64] = fmaf(frac, tb[i].w - ta[i].w, ta[i].w);
    }
    __syncthreads();

    // ---- final slice: g[j in w*12..+12) = bM + h @ M  (M wave-uniform s_load) ----
    float g[12];
    {
        const float* bq = bM + p * 48 + w * 12;
#pragma unroll
        for (int j = 0; j < 12; ++j) g[j] = bq[j];
    }
    const float* __restrict__ mp = M + p * 3072 + w * 12;
#pragma unroll 8
    for (int h = 0; h < 64; ++h) {
        float hv = hbuf[h * 64 + lane];
        const float* wr = mp + h * 48;
#pragma unroll
        for (int j = 0; j < 12; ++j) g[j] = fmaf(hv, wr[j], g[j]);
    }

    if (act) {
        float4* gp = reinterpret_cast<float4*>(gout + (size_t)ci * 48 + w * 12);
#pragma unroll
        for (int i = 0; i < 3; ++i)
            gp[i] = make_float4(g[4 * i], g[4 * i + 1], g[4 * i + 2], g[4 * i + 3]);
    }
}

// ================= per-node aggregation =================

__global__ __launch_bounds__(256) void k_node(
    const int* __restrict__ row_off,
    const float* __restrict__ v4, const float* __restrict__ g,
    int N, float* __restrict__ out)
{
    int tid = threadIdx.x;
    int lane = tid & 63;
    int grp = lane >> 4;
    int o = lane & 15;
    int n = blockIdx.x * 4 + (tid >> 6);
    if (n >= N) return;
    int beg = row_off[n], end = row_off[n + 1];
    float a0 = 0.0f;
    float a1[3] = {0.0f, 0.0f, 0.0f};
    float a2[9] = {0.0f, 0.0f, 0.0f, 0.0f, 0.0f, 0.0f, 0.0f, 0.0f, 0.0f};
    for (int k = beg + grp; k < end; k += 4) {
        const float* ge = g + (size_t)k * 48;
        float g0 = ge[o];
        float g1 = ge[16 + o];
        float g2 = ge[32 + o];
        float4 vv = reinterpret_cast<const float4*>(v4)[k];
        float v[3] = {vv.x, vv.y, vv.z};
        a0 += g0;
#pragma unroll
        for (int d = 0; d < 3; ++d) a1[d] = fmaf(g1, v[d], a1[d]);
#pragma unroll
        for (int d1 = 0; d1 < 3; ++d1) {
            float gv = g2 * v[d1];
#pragma unroll
            for (int d2 = 0; d2 < 3; ++d2)
                a2[d1 * 3 + d2] = fmaf(gv, v[d2], a2[d1 * 3 + d2]);
        }
    }
#pragma unroll
    for (int m = 16; m <= 32; m <<= 1) {
        a0 += __shfl_xor(a0, m, 64);
#pragma unroll
        for (int d = 0; d < 3; ++d) a1[d] += __shfl_xor(a1[d], m, 64);
#pragma unroll
        for (int dd = 0; dd < 9; ++dd) a2[dd] += __shfl_xor(a2[dd], m, 64);
    }
    float cnt = (float)(end - beg);
    float invc = (cnt > 0.0f) ? (1.0f / cnt) : 1.0f;
    float* on = out + (size_t)n * 416;
    if (lane < 52)
        reinterpret_cast<float4*>(on + 208)[lane] = make_float4(0.f, 0.f, 0.f, 0.f);
    if (grp == 0) {
        on[o] = a0 * invc;
#pragma unroll
        for (int d = 0; d < 3; ++d) on[16 + o * 3 + d] = a1[d] * invc;
#pragma unroll
        for (int dd = 0; dd < 9; ++dd) on[64 + o * 9 + dd] = a2[dd] * invc;
    }
}

extern "C" void kernel_launch(void* const* d_in, const int* in_sizes, int n_in,
                              void* d_out, int out_size, void* d_ws, size_t ws_size,
                              hipStream_t stream)
{
    const float* pos         = (const float*)d_in[0];
    const float* edge_shifts = (const float*)d_in[1];
    const float* cell        = (const float*)d_in[2];
    const int*   Aarr        = (const int*)d_in[3];
    const int*   batch       = (const int*)d_in[4];
    const int*   esrc        = (const int*)d_in[5];
    const int*   edst        = (const int*)d_in[6];
    const float* emb_table   = (const float*)d_in[7];
    const float* Wa1         = (const float*)d_in[8];
    const float* ba1         = (const float*)d_in[9];
    const float* Wa2         = (const float*)d_in[10];
    const float* ba2         = (const float*)d_in[11];
    const float* Wf1         = (const float*)d_in[12];
    const float* bf1         = (const float*)d_in[13];
    const float* Wf2         = (const float*)d_in[14];
    const float* bf2         = (const float*)d_in[15];
    const float* Wf3         = (const float*)d_in[16];
    const float* bf3         = (const float*)d_in[17];

    int N = in_sizes[0] / 3;
    int E = in_sizes[5];
    int maxblk = (E + 63) / 64 + NPAIR;
    int nslot = maxblk * 64;
    int nhblk = (E + SCHUNK - 1) / SCHUNK;
    float* out = (float*)d_out;

    char* ws = (char*)d_ws;
    size_t off = 0;
    auto alloc = [&](size_t bytes) -> void* {
        void* p = ws + off;
        off += (bytes + 255) & ~(size_t)255;
        return p;
    };
    float* M       = (float*)alloc((size_t)NPAIR * 3072 * sizeof(float));
    float* bM      = (float*)alloc((size_t)NPAIR * 48 * sizeof(float));
    float* Htab    = (float*)alloc((size_t)TS * 64 * sizeof(float));
    int*   nodecnt = (int*)alloc((size_t)N * sizeof(int));
    int*   rowoff  = (int*)alloc((size_t)(N + 1) * sizeof(int));
    int*   blkhist = (int*)alloc((size_t)nhblk * NPAIR * sizeof(int));
    int*   blkbase = (int*)alloc((size_t)nhblk * NPAIR * sizeof(int));
    int*   info_r  = (int*)alloc((size_t)E * sizeof(int));
    unsigned short* info_p = (unsigned short*)alloc((size_t)E * sizeof(unsigned short));
    int*   b2p     = (int*)alloc((size_t)maxblk * sizeof(int));
    int*   einv    = (int*)alloc((size_t)nslot * sizeof(int));
    float* geo     = (float*)alloc((size_t)nslot * sizeof(float));
    float* v4      = (float*)alloc((size_t)E * 4 * sizeof(float));
    float* g       = (float*)alloc((size_t)E * 48 * sizeof(float));
    (void)ws_size; (void)n_in; (void)out_size;

    hipMemsetAsync(nodecnt, 0, (size_t)N * sizeof(int), stream);
    k_front<<<NPAIR + NB_TAB + nhblk, 256, 0, stream>>>(
        E, esrc, edst, Aarr, nodecnt, blkhist, info_r, info_p,
        emb_table, Wa1, ba1, Wa2, ba2, Wf1, bf1, Wf2, bf2, Wf3, bf3,
        M, bM, Htab);
    k_scan<<<2, 256, 0, stream>>>(nhblk, N, maxblk, nodecnt, blkhist,
                                  rowoff, blkbase, b2p, einv, geo);
    k_scatter<<<nhblk, 256, 0, stream>>>(
        E, esrc, edst, pos, edge_shifts, cell, batch,
        rowoff, blkbase, info_r, info_p, einv, geo, v4);
    k_edge<<<maxblk, 256, 0, stream>>>(b2p, einv, geo, Htab, M, bM, g);
    k_node<<<(N + 3) / 4, 256, 0, stream>>>(rowoff, v4, g, N, out);
}

// Round 5
// 76.449 us; speedup vs baseline: 1.4651x; 1.4651x over previous
//
#include <hip/hip_runtime.h>
#include <math.h>

// PureCartesianE3Conv on MI355X — round 13.
// r10: cg grid.sync ~40us each -> never again.
// r11: redundant per-block scans in scatter cost ~15us.
// r12: scans-once was right, but SERIAL: k_scan = 50us (VALUBusy 0.015%) from
//      the 196-long dependent stride-400B blkbase walk per pair-thread.
// r13: k_scan -> 2x1024 threads, fully parallel:
//      block0 = r9's 1024-thread node scan;
//      block1 = tiled 2-level block/pair prefix (8 chunks x 128 pairs,
//               tid=c*128+p so lanes hold consecutive p -> coalesced),
//               chain length 196->25; spb via 128-wide Hillis-Steele.
// Everything else identical to r12.

#define NPAIR 100
#define SCHUNK 512
#define TS 8192
#define NB_TAB (TS / 64)
#define LSCALE (8192.0f / 7.0f)
#define LSTEP  (7.0f / 8192.0f)

__device__ __forceinline__ float silu_acc(float x) {
    return x / (1.0f + expf(-x));   // precise: setup path only
}

// ================= phase device functions =================

__device__ void d_pairtab(int p, int tid, float* lds,
    const float* emb_table, const float* Wa1, const float* ba1,
    const float* Wa2, const float* ba2,
    const float* Wf3, const float* bf3,
    float* M, float* bM)
{
    int pa = p / 10, pb = p % 10;
    float* sh = lds;             // 128
    float* sP = lds + 128;       // 8
    if (tid < 128) {
        int row = (tid < 64) ? pa : pb;
        int j = tid & 63;
        float a = ba1[j];
#pragma unroll
        for (int k = 0; k < 16; ++k) a = fmaf(emb_table[row * 16 + k], Wa1[k * 64 + j], a);
        sh[tid] = silu_acc(a);
    }
    __syncthreads();
    if (tid < 8) {
        float aa = ba2[tid], ab = ba2[tid];
        for (int j = 0; j < 64; ++j) {
            aa = fmaf(sh[j], Wa2[j * 8 + tid], aa);
            ab = fmaf(sh[64 + j], Wa2[j * 8 + tid], ab);
        }
        sP[tid] = aa * ab;
    }
    __syncthreads();
    for (int base = tid; base < 3072; base += 256) {
        int h = base / 48;
        int j = base - h * 48;
        const float* wr = Wf3 + h * 1536 + (j >> 4) * 128 + (j & 15);
        float a = 0.0f;
#pragma unroll
        for (int c = 0; c < 8; ++c) a = fmaf(sP[c], wr[c * 16], a);
        M[p * 3072 + base] = a;
    }
    if (tid < 48) {
        const float* br = bf3 + (tid >> 4) * 128 + (tid & 15);
        float a = 0.0f;
#pragma unroll
        for (int c = 0; c < 8; ++c) a = fmaf(sP[c], br[c * 16], a);
        bM[p * 48 + tid] = a;
    }
}

__device__ void d_htab(int blk, int tid, float* lds,
    const float* Wf1, const float* bf1, const float* Wf2, const float* bf2,
    float* Htab)
{
    int w = __builtin_amdgcn_readfirstlane(tid >> 6);
    int lane = tid & 63;
    int s = blk * 64 + lane;
    float len = (float)s * LSTEP;
    float ek[8];
#pragma unroll
    for (int k = 0; k < 8; ++k) {
        float d = fmaf(len, 1.8f, -(float)(k + 1));
        ek[k] = expf(-d * d) * 2.5253813613805388f;   // sqrt(8)/1.12
    }
    float t[16];
    {
        const float* bq = bf1 + w * 16;
#pragma unroll
        for (int j = 0; j < 16; ++j) t[j] = bq[j];
#pragma unroll
        for (int k = 0; k < 8; ++k) {
            float e8 = ek[k];
            const float* wr = Wf1 + k * 64 + w * 16;
#pragma unroll
            for (int j = 0; j < 16; ++j) t[j] = fmaf(e8, wr[j], t[j]);
        }
#pragma unroll
        for (int j = 0; j < 16; ++j) lds[(w * 16 + j) * 64 + lane] = silu_acc(t[j]);
    }
    __syncthreads();
    float h2[16];
    {
        const float* bq = bf2 + w * 16;
#pragma unroll
        for (int j = 0; j < 16; ++j) h2[j] = bq[j];
    }
#pragma unroll 8
    for (int k = 0; k < 64; ++k) {
        float hk = lds[k * 64 + lane];
        const float* wr = Wf2 + k * 64 + w * 16;
#pragma unroll
        for (int j = 0; j < 16; ++j) h2[j] = fmaf(hk, wr[j], h2[j]);
    }
    float* tp = Htab + (size_t)s * 64 + w * 16;
#pragma unroll
    for (int j = 0; j < 16; ++j) tp[j] = silu_acc(h2[j]);
}

// ================= front kernel: pairtab | htab | count =================

__global__ __launch_bounds__(256) void k_front(
    int E,
    const int* __restrict__ esrc, const int* __restrict__ edst,
    const int* __restrict__ Aarr,
    int* __restrict__ nodecnt, int* __restrict__ blkhist,
    int* __restrict__ info_r, unsigned short* __restrict__ info_p,
    const float* __restrict__ emb_table, const float* __restrict__ Wa1,
    const float* __restrict__ ba1, const float* __restrict__ Wa2,
    const float* __restrict__ ba2,
    const float* __restrict__ Wf1, const float* __restrict__ bf1,
    const float* __restrict__ Wf2, const float* __restrict__ bf2,
    const float* __restrict__ Wf3, const float* __restrict__ bf3,
    float* __restrict__ M, float* __restrict__ bM, float* __restrict__ Htab)
{
    __shared__ __align__(16) char sm[16384];
    int bid = blockIdx.x;
    int tid = threadIdx.x;

    if (bid < NPAIR) {
        d_pairtab(bid, tid, (float*)sm, emb_table, Wa1, ba1, Wa2, ba2, Wf3, bf3, M, bM);
        return;
    }
    bid -= NPAIR;
    if (bid < NB_TAB) {
        d_htab(bid, tid, (float*)sm, Wf1, bf1, Wf2, bf2, Htab);
        return;
    }
    bid -= NB_TAB;

    // ---- count: rank capture + per-block pair histogram ([b][p] layout) ----
    int* hist = (int*)sm;
    if (tid < NPAIR) hist[tid] = 0;
    __syncthreads();
    int base = bid * SCHUNK;
#pragma unroll
    for (int i = 0; i < SCHUNK / 256; ++i) {
        int e = base + tid + i * 256;
        if (e < E) {
            int d = edst[e];
            int s = esrc[e];
            int rn = atomicAdd(&nodecnt[d], 1);          // global rank within node
            int p = Aarr[s] * 10 + Aarr[d];
            int rp = atomicAdd(&hist[p], 1);             // rank within (block, pair)
            info_r[e] = rn;
            info_p[e] = (unsigned short)((rp << 7) | p); // rp<512 (9b), p<100 (7b)
        }
    }
    __syncthreads();
    if (tid < NPAIR) blkhist[bid * NPAIR + tid] = hist[tid];
}

// ================= scan kernel: 2 blocks x 1024, all parallel =================

__global__ __launch_bounds__(1024) void k_scan(
    int nhblk, int N, int maxblk,
    const int* __restrict__ nodecnt, const int* __restrict__ blkhist,
    int* __restrict__ row_off, int* __restrict__ blkbase,
    int* __restrict__ b2p, int* __restrict__ einv, float* __restrict__ geo)
{
    __shared__ int buf[1024];
    __shared__ int part[8][128];
    __shared__ int tot[128];
    __shared__ int nbp[128];
    __shared__ int spb[NPAIR + 1];
    int tid = threadIdx.x;

    if (blockIdx.x == 0) {
        // ---- node prefix scan -> row_off (1024-thread, r9-proven) ----
        int CH = (N + 1023) / 1024;
        int start = tid * CH, end = min(start + CH, N);
        int s = 0;
        for (int i = start; i < end; ++i) s += nodecnt[i];
        buf[tid] = s;
        __syncthreads();
        for (int o = 1; o < 1024; o <<= 1) {
            int y = (tid >= o) ? buf[tid - o] : 0;
            __syncthreads();
            buf[tid] += y;
            __syncthreads();
        }
        int run = buf[tid] - s;
        for (int i = start; i < end; ++i) {
            int c = nodecnt[i];
            row_off[i] = run;
            run += c;
        }
        if (tid == 1023) row_off[N] = buf[1023];
    } else {
        // ---- tiled 2-level block/pair prefix ----
        int c = tid >> 7;          // chunk 0..7
        int p = tid & 127;         // pair (lanes hold consecutive p -> coalesced)
        int CH2 = (nhblk + 7) / 8;
        int b0 = c * CH2, b1 = min(b0 + CH2, nhblk);
        int s = 0;
        if (p < NPAIR)
            for (int b = b0; b < b1; ++b) s += blkhist[b * NPAIR + p];
        part[c][p] = s;
        __syncthreads();
        // thread p: exclusive scan of its 8 chunk partials (LDS, chain=8)
        if (tid < 128) {
            int run = 0;
#pragma unroll
            for (int cc = 0; cc < 8; ++cc) {
                int v = part[cc][tid];
                part[cc][tid] = run;
                run += v;
            }
            tot[tid] = run;
            nbp[tid] = (tid < NPAIR) ? ((run + 63) >> 6) : 0;
        }
        __syncthreads();
        // 128-wide Hillis-Steele inclusive scan of padded block counts
        for (int o = 1; o < 128; o <<= 1) {
            int y = (tid < 128 && tid >= o) ? nbp[tid - o] : 0;
            __syncthreads();
            if (tid < 128) nbp[tid] += y;
            __syncthreads();
        }
        if (tid < NPAIR) spb[tid] = (tid == 0) ? 0 : nbp[tid - 1] * 64;
        if (tid == 0) spb[NPAIR] = nbp[NPAIR - 1] * 64;
        __syncthreads();
        // phase C: write blkbase (coalesced, chain = CH2)
        if (p < NPAIR) {
            int run = spb[p] + part[c][p];
            for (int b = b0; b < b1; ++b) {
                blkbase[b * NPAIR + p] = run;
                run += blkhist[b * NPAIR + p];
            }
        }
        // b2p init, then fill + slot padding
        for (int b = tid; b < maxblk; b += 1024) b2p[b] = -1;
        __syncthreads();
        if (tid < NPAIR) {
            int ob = spb[tid] >> 6;
            int oe = spb[tid + 1] >> 6;
            for (int b = ob; b < oe; ++b) b2p[b] = tid;
            for (int q = spb[tid] + tot[tid]; q < spb[tid + 1]; ++q) {
                einv[q] = -1;
                geo[q] = 0.0f;
            }
        }
    }
}

// ================= scatter: pure function, no atomics =================

__global__ __launch_bounds__(256) void k_scatter(
    int E,
    const int* __restrict__ esrc, const int* __restrict__ edst,
    const float* __restrict__ pos, const float* __restrict__ edge_shifts,
    const float* __restrict__ cell, const int* __restrict__ batch,
    const int* __restrict__ row_off, const int* __restrict__ blkbase,
    const int* __restrict__ info_r, const unsigned short* __restrict__ info_p,
    int* __restrict__ einv, float* __restrict__ geo, float* __restrict__ v4)
{
    __shared__ int sbase[NPAIR];
    int tid = threadIdx.x;
    int bid = blockIdx.x;
    if (tid < NPAIR) sbase[tid] = blkbase[bid * NPAIR + tid];
    __syncthreads();
    int base = bid * SCHUNK;
#pragma unroll
    for (int i = 0; i < SCHUNK / 256; ++i) {
        int e = base + tid + i * 256;
        if (e < E) {
            int d = edst[e];
            int src = esrc[e];
            int rn = info_r[e];
            int ip = (int)info_p[e];
            int p = ip & 127;
            int rp = ip >> 7;
            int slot = sbase[p] + rp;
            int s2v = row_off[d] + rn;
            einv[slot] = s2v;
            int b = batch[src];
            float s0 = edge_shifts[e * 3 + 0];
            float s1 = edge_shifts[e * 3 + 1];
            float s2 = edge_shifts[e * 3 + 2];
            const float* cm = cell + b * 9;
            float ev0 = pos[d * 3 + 0] - pos[src * 3 + 0] + s0 * cm[0] + s1 * cm[3] + s2 * cm[6];
            float ev1 = pos[d * 3 + 1] - pos[src * 3 + 1] + s0 * cm[1] + s1 * cm[4] + s2 * cm[7];
            float ev2 = pos[d * 3 + 2] - pos[src * 3 + 2] + s0 * cm[2] + s1 * cm[5] + s2 * cm[8];
            float len = sqrtf(ev0 * ev0 + ev1 * ev1 + ev2 * ev2);
            float inv = 1.0f / (len + 1e-12f);
            reinterpret_cast<float4*>(v4)[s2v] =
                make_float4(ev0 * inv, ev1 * inv, ev2 * inv, len);
            geo[slot] = len * LSCALE;
        }
    }
}

// ================= fused per-edge kernel =================

__global__ __launch_bounds__(256, 6) void k_edge(
    const int* __restrict__ b2p, const int* __restrict__ einv,
    const float* __restrict__ geo, const float* __restrict__ Htab,
    const float* __restrict__ M, const float* __restrict__ bM,
    float* __restrict__ gout)
{
    __shared__ float hbuf[64 * 64];  // 16 KB, [k][lane]
    int p = b2p[blockIdx.x];
    if (p < 0) return;
    p = __builtin_amdgcn_readfirstlane(p);
    int tid = threadIdx.x;
    int w = __builtin_amdgcn_readfirstlane(tid >> 6);  // wave id 0..3, SGPR
    int lane = tid & 63;
    int slot = blockIdx.x * 64 + lane;
    int ci = einv[slot];
    bool act = ci >= 0;

    // ---- fill hbuf via table gather + linear interp (wave w fills k in [w*16,+16)) ----
    float u = geo[slot];                       // len * LSCALE (0 for padding)
    int i0 = (int)u;
    i0 = min(max(i0, 0), TS - 2);
    float frac = u - (float)i0;
    const float4* r0 = reinterpret_cast<const float4*>(Htab + (size_t)i0 * 64 + w * 16);
    float4 ta[4], tb[4];
#pragma unroll
    for (int i = 0; i < 4; ++i) { ta[i] = r0[i]; tb[i] = r0[i + 16]; }  // +16 f4 = next row
    float* hb = hbuf + (w * 16) * 64 + lane;
#pragma unroll
    for (int i = 0; i < 4; ++i) {
        hb[(4 * i + 0) * 64] = fmaf(frac, tb[i].x - ta[i].x, ta[i].x);
        hb[(4 * i + 1) * 64] = fmaf(frac, tb[i].y - ta[i].y, ta[i].y);
        hb[(4 * i + 2) * 64] = fmaf(frac, tb[i].z - ta[i].z, ta[i].z);
        hb[(4 * i + 3) * 64] = fmaf(frac, tb[i].w - ta[i].w, ta[i].w);
    }
    __syncthreads();

    // ---- final slice: g[j in w*12..+12) = bM + h @ M  (M wave-uniform s_load) ----
    float g[12];
    {
        const float* bq = bM + p * 48 + w * 12;
#pragma unroll
        for (int j = 0; j < 12; ++j) g[j] = bq[j];
    }
    const float* __restrict__ mp = M + p * 3072 + w * 12;
#pragma unroll 8
    for (int h = 0; h < 64; ++h) {
        float hv = hbuf[h * 64 + lane];
        const float* wr = mp + h * 48;
#pragma unroll
        for (int j = 0; j < 12; ++j) g[j] = fmaf(hv, wr[j], g[j]);
    }

    if (act) {
        float4* gp = reinterpret_cast<float4*>(gout + (size_t)ci * 48 + w * 12);
#pragma unroll
        for (int i = 0; i < 3; ++i)
            gp[i] = make_float4(g[4 * i], g[4 * i + 1], g[4 * i + 2], g[4 * i + 3]);
    }
}

// ================= per-node aggregation =================

__global__ __launch_bounds__(256) void k_node(
    const int* __restrict__ row_off,
    const float* __restrict__ v4, const float* __restrict__ g,
    int N, float* __restrict__ out)
{
    int tid = threadIdx.x;
    int lane = tid & 63;
    int grp = lane >> 4;
    int o = lane & 15;
    int n = blockIdx.x * 4 + (tid >> 6);
    if (n >= N) return;
    int beg = row_off[n], end = row_off[n + 1];
    float a0 = 0.0f;
    float a1[3] = {0.0f, 0.0f, 0.0f};
    float a2[9] = {0.0f, 0.0f, 0.0f, 0.0f, 0.0f, 0.0f, 0.0f, 0.0f, 0.0f};
    for (int k = beg + grp; k < end; k += 4) {
        const float* ge = g + (size_t)k * 48;
        float g0 = ge[o];
        float g1 = ge[16 + o];
        float g2 = ge[32 + o];
        float4 vv = reinterpret_cast<const float4*>(v4)[k];
        float v[3] = {vv.x, vv.y, vv.z};
        a0 += g0;
#pragma unroll
        for (int d = 0; d < 3; ++d) a1[d] = fmaf(g1, v[d], a1[d]);
#pragma unroll
        for (int d1 = 0; d1 < 3; ++d1) {
            float gv = g2 * v[d1];
#pragma unroll
            for (int d2 = 0; d2 < 3; ++d2)
                a2[d1 * 3 + d2] = fmaf(gv, v[d2], a2[d1 * 3 + d2]);
        }
    }
#pragma unroll
    for (int m = 16; m <= 32; m <<= 1) {
        a0 += __shfl_xor(a0, m, 64);
#pragma unroll
        for (int d = 0; d < 3; ++d) a1[d] += __shfl_xor(a1[d], m, 64);
#pragma unroll
        for (int dd = 0; dd < 9; ++dd) a2[dd] += __shfl_xor(a2[dd], m, 64);
    }
    float cnt = (float)(end - beg);
    float invc = (cnt > 0.0f) ? (1.0f / cnt) : 1.0f;
    float* on = out + (size_t)n * 416;
    if (lane < 52)
        reinterpret_cast<float4*>(on + 208)[lane] = make_float4(0.f, 0.f, 0.f, 0.f);
    if (grp == 0) {
        on[o] = a0 * invc;
#pragma unroll
        for (int d = 0; d < 3; ++d) on[16 + o * 3 + d] = a1[d] * invc;
#pragma unroll
        for (int dd = 0; dd < 9; ++dd) on[64 + o * 9 + dd] = a2[dd] * invc;
    }
}

extern "C" void kernel_launch(void* const* d_in, const int* in_sizes, int n_in,
                              void* d_out, int out_size, void* d_ws, size_t ws_size,
                              hipStream_t stream)
{
    const float* pos         = (const float*)d_in[0];
    const float* edge_shifts = (const float*)d_in[1];
    const float* cell        = (const float*)d_in[2];
    const int*   Aarr        = (const int*)d_in[3];
    const int*   batch       = (const int*)d_in[4];
    const int*   esrc        = (const int*)d_in[5];
    const int*   edst        = (const int*)d_in[6];
    const float* emb_table   = (const float*)d_in[7];
    const float* Wa1         = (const float*)d_in[8];
    const float* ba1         = (const float*)d_in[9];
    const float* Wa2         = (const float*)d_in[10];
    const float* ba2         = (const float*)d_in[11];
    const float* Wf1         = (const float*)d_in[12];
    const float* bf1         = (const float*)d_in[13];
    const float* Wf2         = (const float*)d_in[14];
    const float* bf2         = (const float*)d_in[15];
    const float* Wf3         = (const float*)d_in[16];
    const float* bf3         = (const float*)d_in[17];

    int N = in_sizes[0] / 3;
    int E = in_sizes[5];
    int maxblk = (E + 63) / 64 + NPAIR;
    int nslot = maxblk * 64;
    int nhblk = (E + SCHUNK - 1) / SCHUNK;
    float* out = (float*)d_out;

    char* ws = (char*)d_ws;
    size_t off = 0;
    auto alloc = [&](size_t bytes) -> void* {
        void* p = ws + off;
        off += (bytes + 255) & ~(size_t)255;
        return p;
    };
    float* M       = (float*)alloc((size_t)NPAIR * 3072 * sizeof(float));
    float* bM      = (float*)alloc((size_t)NPAIR * 48 * sizeof(float));
    float* Htab    = (float*)alloc((size_t)TS * 64 * sizeof(float));
    int*   nodecnt = (int*)alloc((size_t)N * sizeof(int));
    int*   rowoff  = (int*)alloc((size_t)(N + 1) * sizeof(int));
    int*   blkhist = (int*)alloc((size_t)nhblk * NPAIR * sizeof(int));
    int*   blkbase = (int*)alloc((size_t)nhblk * NPAIR * sizeof(int));
    int*   info_r  = (int*)alloc((size_t)E * sizeof(int));
    unsigned short* info_p = (unsigned short*)alloc((size_t)E * sizeof(unsigned short));
    int*   b2p     = (int*)alloc((size_t)maxblk * sizeof(int));
    int*   einv    = (int*)alloc((size_t)nslot * sizeof(int));
    float* geo     = (float*)alloc((size_t)nslot * sizeof(float));
    float* v4      = (float*)alloc((size_t)E * 4 * sizeof(float));
    float* g       = (float*)alloc((size_t)E * 48 * sizeof(float));
    (void)ws_size; (void)n_in; (void)out_size;

    hipMemsetAsync(nodecnt, 0, (size_t)N * sizeof(int), stream);
    k_front<<<NPAIR + NB_TAB + nhblk, 256, 0, stream>>>(
        E, esrc, edst, Aarr, nodecnt, blkhist, info_r, info_p,
        emb_table, Wa1, ba1, Wa2, ba2, Wf1, bf1, Wf2, bf2, Wf3, bf3,
        M, bM, Htab);
    k_scan<<<2, 1024, 0, stream>>>(nhblk, N, maxblk, nodecnt, blkhist,
                                   rowoff, blkbase, b2p, einv, geo);
    k_scatter<<<nhblk, 256, 0, stream>>>(
        E, esrc, edst, pos, edge_shifts, cell, batch,
        rowoff, blkbase, info_r, info_p, einv, geo, v4);
    k_edge<<<maxblk, 256, 0, stream>>>(b2p, einv, geo, Htab, M, bM, g);
    k_node<<<(N + 3) / 4, 256, 0, stream>>>(rowoff, v4, g, N, out);
}

// Round 6
// 68.768 us; speedup vs baseline: 1.6287x; 1.1117x over previous
//
#include <hip/hip_runtime.h>
#include <math.h>

// PureCartesianE3Conv on MI355X — round 14.
// r10: cg grid.sync ~40us -> never. r12: serial scan 50us. r13: parallel scan
// -> 76us, no kernel dominates; cost is ~6 dispatches + gaps.
// r14: eliminate BOTH prefix scans via fixed-capacity layouts:
//   pair slots: slot = p*2048 + rank  (rank: LDS hist + pcur[p] atomic)
//               -> k_edge pair id is STATIC (p = bid>>5), no b2p/blkbase/scan;
//                  empty blocks early-exit on uniform ballot.
//   node CSR:   ci = node*64 + rank   (rank: nodecnt atomic)
//               -> k_node uses beg=n<<6, deg=nodecnt[n]; no row_off.
//   => scatter has no scan dependency -> folded into count (k_front).
// Pipeline: memset(860KB zeros) -> k_front(pairtab|htab|count+scatter)
//           -> k_edge -> k_node.  4 dispatches (was 6).
// einv stores ci+1 so memset(0) marks padding; poisoned geo in padding lanes
// is NaN-contained (lane-private hbuf columns, guarded writes).

#define NPAIR 100
#define SCHUNK 512
#define TS 8192
#define NB_TAB (TS / 64)
#define LSCALE (8192.0f / 7.0f)
#define LSTEP  (7.0f / 8192.0f)
#define PCAP 2048                 // slots per pair (counts ~1000 +- ~100)
#define NCAP 64                   // slots per node (degree ~Poisson(10))
#define NSLOT (NPAIR * PCAP)

__device__ __forceinline__ float silu_acc(float x) {
    return x / (1.0f + expf(-x));   // precise: setup path only
}

// ================= phase device functions =================

__device__ void d_pairtab(int p, int tid, float* lds,
    const float* emb_table, const float* Wa1, const float* ba1,
    const float* Wa2, const float* ba2,
    const float* Wf3, const float* bf3,
    float* M, float* bM)
{
    int pa = p / 10, pb = p % 10;
    float* sh = lds;             // 128
    float* sP = lds + 128;       // 8
    if (tid < 128) {
        int row = (tid < 64) ? pa : pb;
        int j = tid & 63;
        float a = ba1[j];
#pragma unroll
        for (int k = 0; k < 16; ++k) a = fmaf(emb_table[row * 16 + k], Wa1[k * 64 + j], a);
        sh[tid] = silu_acc(a);
    }
    __syncthreads();
    if (tid < 8) {
        float aa = ba2[tid], ab = ba2[tid];
        for (int j = 0; j < 64; ++j) {
            aa = fmaf(sh[j], Wa2[j * 8 + tid], aa);
            ab = fmaf(sh[64 + j], Wa2[j * 8 + tid], ab);
        }
        sP[tid] = aa * ab;
    }
    __syncthreads();
    for (int base = tid; base < 3072; base += 256) {
        int h = base / 48;
        int j = base - h * 48;
        const float* wr = Wf3 + h * 1536 + (j >> 4) * 128 + (j & 15);
        float a = 0.0f;
#pragma unroll
        for (int c = 0; c < 8; ++c) a = fmaf(sP[c], wr[c * 16], a);
        M[p * 3072 + base] = a;
    }
    if (tid < 48) {
        const float* br = bf3 + (tid >> 4) * 128 + (tid & 15);
        float a = 0.0f;
#pragma unroll
        for (int c = 0; c < 8; ++c) a = fmaf(sP[c], br[c * 16], a);
        bM[p * 48 + tid] = a;
    }
}

__device__ void d_htab(int blk, int tid, float* lds,
    const float* Wf1, const float* bf1, const float* Wf2, const float* bf2,
    float* Htab)
{
    int w = __builtin_amdgcn_readfirstlane(tid >> 6);
    int lane = tid & 63;
    int s = blk * 64 + lane;
    float len = (float)s * LSTEP;
    float ek[8];
#pragma unroll
    for (int k = 0; k < 8; ++k) {
        float d = fmaf(len, 1.8f, -(float)(k + 1));
        ek[k] = expf(-d * d) * 2.5253813613805388f;   // sqrt(8)/1.12
    }
    float t[16];
    {
        const float* bq = bf1 + w * 16;
#pragma unroll
        for (int j = 0; j < 16; ++j) t[j] = bq[j];
#pragma unroll
        for (int k = 0; k < 8; ++k) {
            float e8 = ek[k];
            const float* wr = Wf1 + k * 64 + w * 16;
#pragma unroll
            for (int j = 0; j < 16; ++j) t[j] = fmaf(e8, wr[j], t[j]);
        }
#pragma unroll
        for (int j = 0; j < 16; ++j) lds[(w * 16 + j) * 64 + lane] = silu_acc(t[j]);
    }
    __syncthreads();
    float h2[16];
    {
        const float* bq = bf2 + w * 16;
#pragma unroll
        for (int j = 0; j < 16; ++j) h2[j] = bq[j];
    }
#pragma unroll 8
    for (int k = 0; k < 64; ++k) {
        float hk = lds[k * 64 + lane];
        const float* wr = Wf2 + k * 64 + w * 16;
#pragma unroll
        for (int j = 0; j < 16; ++j) h2[j] = fmaf(hk, wr[j], h2[j]);
    }
    float* tp = Htab + (size_t)s * 64 + w * 16;
#pragma unroll
    for (int j = 0; j < 16; ++j) tp[j] = silu_acc(h2[j]);
}

// ================= front kernel: pairtab | htab | count+scatter =================

__global__ __launch_bounds__(256) void k_front(
    int E,
    const int* __restrict__ esrc, const int* __restrict__ edst,
    const int* __restrict__ Aarr,
    const float* __restrict__ pos, const float* __restrict__ edge_shifts,
    const float* __restrict__ cell, const int* __restrict__ batch,
    int* __restrict__ nodecnt, int* __restrict__ pcur,
    int* __restrict__ einv, float* __restrict__ geo, float* __restrict__ v4,
    const float* __restrict__ emb_table, const float* __restrict__ Wa1,
    const float* __restrict__ ba1, const float* __restrict__ Wa2,
    const float* __restrict__ ba2,
    const float* __restrict__ Wf1, const float* __restrict__ bf1,
    const float* __restrict__ Wf2, const float* __restrict__ bf2,
    const float* __restrict__ Wf3, const float* __restrict__ bf3,
    float* __restrict__ M, float* __restrict__ bM, float* __restrict__ Htab)
{
    __shared__ __align__(16) char sm[16384];
    int bid = blockIdx.x;
    int tid = threadIdx.x;

    if (bid < NPAIR) {
        d_pairtab(bid, tid, (float*)sm, emb_table, Wa1, ba1, Wa2, ba2, Wf3, bf3, M, bM);
        return;
    }
    bid -= NPAIR;
    if (bid < NB_TAB) {
        d_htab(bid, tid, (float*)sm, Wf1, bf1, Wf2, bf2, Htab);
        return;
    }
    bid -= NB_TAB;

    // ---- count + scatter fused (no scan dependency) ----
    int* hist = (int*)sm;                 // [NPAIR]
    int* gbase = hist + NPAIR;            // [NPAIR]
    if (tid < NPAIR) hist[tid] = 0;
    __syncthreads();
    int base = bid * SCHUNK;
    int dv[2], sv[2], pv[2], rn[2], rp[2];
#pragma unroll
    for (int i = 0; i < 2; ++i) {
        int e = base + tid + i * 256;
        if (e < E) {
            dv[i] = edst[e];
            sv[i] = esrc[e];
            pv[i] = Aarr[sv[i]] * 10 + Aarr[dv[i]];
            rn[i] = atomicAdd(&nodecnt[dv[i]], 1);    // rank within node
            rp[i] = atomicAdd(&hist[pv[i]], 1);       // rank within (block,pair)
        }
    }
    __syncthreads();
    if (tid < NPAIR && hist[tid] > 0) gbase[tid] = atomicAdd(&pcur[tid], hist[tid]);
    __syncthreads();
#pragma unroll
    for (int i = 0; i < 2; ++i) {
        int e = base + tid + i * 256;
        if (e < E) {
            int d = dv[i], src = sv[i], p = pv[i];
            int prank = gbase[p] + rp[i];
            if (rn[i] < NCAP && prank < PCAP) {       // impossible overflow guard
                int slot = p * PCAP + prank;
                int ci = (d << 6) + rn[i];
                einv[slot] = ci + 1;                  // 0 = padding (memset)
                int b = batch[src];
                float s0 = edge_shifts[e * 3 + 0];
                float s1 = edge_shifts[e * 3 + 1];
                float s2 = edge_shifts[e * 3 + 2];
                const float* cm = cell + b * 9;
                float ev0 = pos[d * 3 + 0] - pos[src * 3 + 0] + s0 * cm[0] + s1 * cm[3] + s2 * cm[6];
                float ev1 = pos[d * 3 + 1] - pos[src * 3 + 1] + s0 * cm[1] + s1 * cm[4] + s2 * cm[7];
                float ev2 = pos[d * 3 + 2] - pos[src * 3 + 2] + s0 * cm[2] + s1 * cm[5] + s2 * cm[8];
                float len = sqrtf(ev0 * ev0 + ev1 * ev1 + ev2 * ev2);
                float inv = 1.0f / (len + 1e-12f);
                reinterpret_cast<float4*>(v4)[ci] =
                    make_float4(ev0 * inv, ev1 * inv, ev2 * inv, len);
                geo[slot] = len * LSCALE;
            }
        }
    }
}

// ================= fused per-edge kernel (static pair id) =================

__global__ __launch_bounds__(256, 6) void k_edge(
    const int* __restrict__ einv, const float* __restrict__ geo,
    const float* __restrict__ Htab,
    const float* __restrict__ M, const float* __restrict__ bM,
    float* __restrict__ gout)
{
    __shared__ float hbuf[64 * 64];  // 16 KB, [k][lane]
    int bid = blockIdx.x;
    int tid = threadIdx.x;
    int lane = tid & 63;
    int slot = bid * 64 + lane;      // grid = NPAIR * (PCAP/64) -> global slot id
    int ev = einv[slot];
    // all 4 waves read identical slots -> uniform decision, safe before barrier
    if (__ballot(ev > 0) == 0ULL) return;
    int p = __builtin_amdgcn_readfirstlane(bid >> 5);   // PCAP/64 = 32 blocks/pair
    int w = __builtin_amdgcn_readfirstlane(tid >> 6);
    bool act = ev > 0;
    int ci = ev - 1;

    // ---- fill hbuf via table gather + linear interp (wave w fills k in [w*16,+16)) ----
    float u = geo[slot];                       // len * LSCALE (garbage in padding: contained)
    int i0 = (int)u;
    i0 = min(max(i0, 0), TS - 2);
    float frac = u - (float)i0;
    const float4* r0 = reinterpret_cast<const float4*>(Htab + (size_t)i0 * 64 + w * 16);
    float4 ta[4], tb[4];
#pragma unroll
    for (int i = 0; i < 4; ++i) { ta[i] = r0[i]; tb[i] = r0[i + 16]; }  // +16 f4 = next row
    float* hb = hbuf + (w * 16) * 64 + lane;
#pragma unroll
    for (int i = 0; i < 4; ++i) {
        hb[(4 * i + 0) * 64] = fmaf(frac, tb[i].x - ta[i].x, ta[i].x);
        hb[(4 * i + 1) * 64] = fmaf(frac, tb[i].y - ta[i].y, ta[i].y);
        hb[(4 * i + 2) * 64] = fmaf(frac, tb[i].z - ta[i].z, ta[i].z);
        hb[(4 * i + 3) * 64] = fmaf(frac, tb[i].w - ta[i].w, ta[i].w);
    }
    __syncthreads();

    // ---- final slice: g[j in w*12..+12) = bM + h @ M  (M wave-uniform s_load) ----
    float g[12];
    {
        const float* bq = bM + p * 48 + w * 12;
#pragma unroll
        for (int j = 0; j < 12; ++j) g[j] = bq[j];
    }
    const float* __restrict__ mp = M + p * 3072 + w * 12;
#pragma unroll 8
    for (int h = 0; h < 64; ++h) {
        float hv = hbuf[h * 64 + lane];
        const float* wr = mp + h * 48;
#pragma unroll
        for (int j = 0; j < 12; ++j) g[j] = fmaf(hv, wr[j], g[j]);
    }

    if (act) {
        float4* gp = reinterpret_cast<float4*>(gout + (size_t)ci * 48 + w * 12);
#pragma unroll
        for (int i = 0; i < 3; ++i)
            gp[i] = make_float4(g[4 * i], g[4 * i + 1], g[4 * i + 2], g[4 * i + 3]);
    }
}

// ================= per-node aggregation (fixed-cap CSR) =================

__global__ __launch_bounds__(256) void k_node(
    const int* __restrict__ nodecnt,
    const float* __restrict__ v4, const float* __restrict__ g,
    int N, float* __restrict__ out)
{
    int tid = threadIdx.x;
    int lane = tid & 63;
    int grp = lane >> 4;
    int o = lane & 15;
    int n = blockIdx.x * 4 + (tid >> 6);
    if (n >= N) return;
    int beg = n << 6;
    int deg = min(nodecnt[n], NCAP);
    int end = beg + deg;
    float a0 = 0.0f;
    float a1[3] = {0.0f, 0.0f, 0.0f};
    float a2[9] = {0.0f, 0.0f, 0.0f, 0.0f, 0.0f, 0.0f, 0.0f, 0.0f, 0.0f};
    for (int k = beg + grp; k < end; k += 4) {
        const float* ge = g + (size_t)k * 48;
        float g0 = ge[o];
        float g1 = ge[16 + o];
        float g2 = ge[32 + o];
        float4 vv = reinterpret_cast<const float4*>(v4)[k];
        float v[3] = {vv.x, vv.y, vv.z};
        a0 += g0;
#pragma unroll
        for (int d = 0; d < 3; ++d) a1[d] = fmaf(g1, v[d], a1[d]);
#pragma unroll
        for (int d1 = 0; d1 < 3; ++d1) {
            float gv = g2 * v[d1];
#pragma unroll
            for (int d2 = 0; d2 < 3; ++d2)
                a2[d1 * 3 + d2] = fmaf(gv, v[d2], a2[d1 * 3 + d2]);
        }
    }
#pragma unroll
    for (int m = 16; m <= 32; m <<= 1) {
        a0 += __shfl_xor(a0, m, 64);
#pragma unroll
        for (int d = 0; d < 3; ++d) a1[d] += __shfl_xor(a1[d], m, 64);
#pragma unroll
        for (int dd = 0; dd < 9; ++dd) a2[dd] += __shfl_xor(a2[dd], m, 64);
    }
    float cnt = (float)deg;
    float invc = (cnt > 0.0f) ? (1.0f / cnt) : 1.0f;
    float* on = out + (size_t)n * 416;
    if (lane < 52)
        reinterpret_cast<float4*>(on + 208)[lane] = make_float4(0.f, 0.f, 0.f, 0.f);
    if (grp == 0) {
        on[o] = a0 * invc;
#pragma unroll
        for (int d = 0; d < 3; ++d) on[16 + o * 3 + d] = a1[d] * invc;
#pragma unroll
        for (int dd = 0; dd < 9; ++dd) on[64 + o * 9 + dd] = a2[dd] * invc;
    }
}

extern "C" void kernel_launch(void* const* d_in, const int* in_sizes, int n_in,
                              void* d_out, int out_size, void* d_ws, size_t ws_size,
                              hipStream_t stream)
{
    const float* pos         = (const float*)d_in[0];
    const float* edge_shifts = (const float*)d_in[1];
    const float* cell        = (const float*)d_in[2];
    const int*   Aarr        = (const int*)d_in[3];
    const int*   batch       = (const int*)d_in[4];
    const int*   esrc        = (const int*)d_in[5];
    const int*   edst        = (const int*)d_in[6];
    const float* emb_table   = (const float*)d_in[7];
    const float* Wa1         = (const float*)d_in[8];
    const float* ba1         = (const float*)d_in[9];
    const float* Wa2         = (const float*)d_in[10];
    const float* ba2         = (const float*)d_in[11];
    const float* Wf1         = (const float*)d_in[12];
    const float* bf1         = (const float*)d_in[13];
    const float* Wf2         = (const float*)d_in[14];
    const float* bf2         = (const float*)d_in[15];
    const float* Wf3         = (const float*)d_in[16];
    const float* bf3         = (const float*)d_in[17];

    int N = in_sizes[0] / 3;
    int E = in_sizes[5];
    int nhblk = (E + SCHUNK - 1) / SCHUNK;
    float* out = (float*)d_out;

    char* ws = (char*)d_ws;
    size_t off = 0;
    auto alloc = [&](size_t bytes) -> void* {
        void* p = ws + off;
        off += (bytes + 255) & ~(size_t)255;
        return p;
    };
    float* M       = (float*)alloc((size_t)NPAIR * 3072 * sizeof(float));
    float* bM      = (float*)alloc((size_t)NPAIR * 48 * sizeof(float));
    float* Htab    = (float*)alloc((size_t)TS * 64 * sizeof(float));
    // --- contiguous zero-init span: nodecnt | pcur | einv ---
    int*   nodecnt = (int*)alloc((size_t)N * sizeof(int));
    int*   pcur    = (int*)alloc((size_t)NPAIR * sizeof(int));
    int*   einv    = (int*)alloc((size_t)NSLOT * sizeof(int));
    size_t zspan   = (size_t)((char*)einv + (size_t)NSLOT * sizeof(int) - (char*)nodecnt);
    // --- uninitialized ---
    float* geo     = (float*)alloc((size_t)NSLOT * sizeof(float));
    float* v4      = (float*)alloc((size_t)N * NCAP * 4 * sizeof(float));
    float* g       = (float*)alloc((size_t)N * NCAP * 48 * sizeof(float));
    (void)ws_size; (void)n_in; (void)out_size;

    hipMemsetAsync(nodecnt, 0, zspan, stream);
    k_front<<<NPAIR + NB_TAB + nhblk, 256, 0, stream>>>(
        E, esrc, edst, Aarr, pos, edge_shifts, cell, batch,
        nodecnt, pcur, einv, geo, v4,
        emb_table, Wa1, ba1, Wa2, ba2, Wf1, bf1, Wf2, bf2, Wf3, bf3,
        M, bM, Htab);
    k_edge<<<NPAIR * (PCAP / 64), 256, 0, stream>>>(einv, geo, Htab, M, bM, g);
    k_node<<<(N + 3) / 4, 256, 0, stream>>>(nodecnt, v4, g, N, out);
}

// Round 7
// 68.362 us; speedup vs baseline: 1.6384x; 1.0059x over previous
//
#include <hip/hip_runtime.h>
#include <math.h>

// PureCartesianE3Conv on MI355X — round 15.
// r14 post-mortem: rocprof showed OUR hipMemsetAsync (fillBufferAligned,
// WRITE_SIZE=839.75KB) costs 39.8us — the runtime blit has a ~40us floor
// regardless of size (the 256MB harness fill takes the same 39.8us). It was
// ~58% of the window, hiding among harness fills since r9.
// r15: (a) replace hipMemsetAsync with a 40-block k_zero kernel (~2us);
//      (b) shrink zero-set 860KB -> 40.6KB: k_edge derives padding from
//          cnt=min(pcur[p],PCAP) (wave-uniform s_load) instead of zeroed einv;
//          einv stores ci directly; garbage in padding slots is lane-contained
//          (clamped table index, act-guarded writes) as r14's geo already was.
// Pipeline: k_zero -> k_front(pairtab|htab|count+scatter) -> k_edge -> k_node.

#define NPAIR 100
#define SCHUNK 512
#define TS 8192
#define NB_TAB (TS / 64)
#define LSCALE (8192.0f / 7.0f)
#define LSTEP  (7.0f / 8192.0f)
#define PCAP 2048                 // slots per pair (counts ~1000 +- ~100)
#define NCAP 64                   // slots per node (degree ~Poisson(10))
#define NSLOT (NPAIR * PCAP)

__device__ __forceinline__ float silu_acc(float x) {
    return x / (1.0f + expf(-x));   // precise: setup path only
}

// ================= zero kernel (replaces 40us fillBufferAligned blit) =================

__global__ __launch_bounds__(256) void k_zero(int* __restrict__ p, int n) {
    int i = blockIdx.x * 256 + threadIdx.x;
    if (i < n) p[i] = 0;
}

// ================= phase device functions =================

__device__ void d_pairtab(int p, int tid, float* lds,
    const float* emb_table, const float* Wa1, const float* ba1,
    const float* Wa2, const float* ba2,
    const float* Wf3, const float* bf3,
    float* M, float* bM)
{
    int pa = p / 10, pb = p % 10;
    float* sh = lds;             // 128
    float* sP = lds + 128;       // 8
    if (tid < 128) {
        int row = (tid < 64) ? pa : pb;
        int j = tid & 63;
        float a = ba1[j];
#pragma unroll
        for (int k = 0; k < 16; ++k) a = fmaf(emb_table[row * 16 + k], Wa1[k * 64 + j], a);
        sh[tid] = silu_acc(a);
    }
    __syncthreads();
    if (tid < 8) {
        float aa = ba2[tid], ab = ba2[tid];
        for (int j = 0; j < 64; ++j) {
            aa = fmaf(sh[j], Wa2[j * 8 + tid], aa);
            ab = fmaf(sh[64 + j], Wa2[j * 8 + tid], ab);
        }
        sP[tid] = aa * ab;
    }
    __syncthreads();
    for (int base = tid; base < 3072; base += 256) {
        int h = base / 48;
        int j = base - h * 48;
        const float* wr = Wf3 + h * 1536 + (j >> 4) * 128 + (j & 15);
        float a = 0.0f;
#pragma unroll
        for (int c = 0; c < 8; ++c) a = fmaf(sP[c], wr[c * 16], a);
        M[p * 3072 + base] = a;
    }
    if (tid < 48) {
        const float* br = bf3 + (tid >> 4) * 128 + (tid & 15);
        float a = 0.0f;
#pragma unroll
        for (int c = 0; c < 8; ++c) a = fmaf(sP[c], br[c * 16], a);
        bM[p * 48 + tid] = a;
    }
}

__device__ void d_htab(int blk, int tid, float* lds,
    const float* Wf1, const float* bf1, const float* Wf2, const float* bf2,
    float* Htab)
{
    int w = __builtin_amdgcn_readfirstlane(tid >> 6);
    int lane = tid & 63;
    int s = blk * 64 + lane;
    float len = (float)s * LSTEP;
    float ek[8];
#pragma unroll
    for (int k = 0; k < 8; ++k) {
        float d = fmaf(len, 1.8f, -(float)(k + 1));
        ek[k] = expf(-d * d) * 2.5253813613805388f;   // sqrt(8)/1.12
    }
    float t[16];
    {
        const float* bq = bf1 + w * 16;
#pragma unroll
        for (int j = 0; j < 16; ++j) t[j] = bq[j];
#pragma unroll
        for (int k = 0; k < 8; ++k) {
            float e8 = ek[k];
            const float* wr = Wf1 + k * 64 + w * 16;
#pragma unroll
            for (int j = 0; j < 16; ++j) t[j] = fmaf(e8, wr[j], t[j]);
        }
#pragma unroll
        for (int j = 0; j < 16; ++j) lds[(w * 16 + j) * 64 + lane] = silu_acc(t[j]);
    }
    __syncthreads();
    float h2[16];
    {
        const float* bq = bf2 + w * 16;
#pragma unroll
        for (int j = 0; j < 16; ++j) h2[j] = bq[j];
    }
#pragma unroll 8
    for (int k = 0; k < 64; ++k) {
        float hk = lds[k * 64 + lane];
        const float* wr = Wf2 + k * 64 + w * 16;
#pragma unroll
        for (int j = 0; j < 16; ++j) h2[j] = fmaf(hk, wr[j], h2[j]);
    }
    float* tp = Htab + (size_t)s * 64 + w * 16;
#pragma unroll
    for (int j = 0; j < 16; ++j) tp[j] = silu_acc(h2[j]);
}

// ================= front kernel: pairtab | htab | count+scatter =================

__global__ __launch_bounds__(256) void k_front(
    int E,
    const int* __restrict__ esrc, const int* __restrict__ edst,
    const int* __restrict__ Aarr,
    const float* __restrict__ pos, const float* __restrict__ edge_shifts,
    const float* __restrict__ cell, const int* __restrict__ batch,
    int* __restrict__ nodecnt, int* __restrict__ pcur,
    int* __restrict__ einv, float* __restrict__ geo, float* __restrict__ v4,
    const float* __restrict__ emb_table, const float* __restrict__ Wa1,
    const float* __restrict__ ba1, const float* __restrict__ Wa2,
    const float* __restrict__ ba2,
    const float* __restrict__ Wf1, const float* __restrict__ bf1,
    const float* __restrict__ Wf2, const float* __restrict__ bf2,
    const float* __restrict__ Wf3, const float* __restrict__ bf3,
    float* __restrict__ M, float* __restrict__ bM, float* __restrict__ Htab)
{
    __shared__ __align__(16) char sm[16384];
    int bid = blockIdx.x;
    int tid = threadIdx.x;

    if (bid < NPAIR) {
        d_pairtab(bid, tid, (float*)sm, emb_table, Wa1, ba1, Wa2, ba2, Wf3, bf3, M, bM);
        return;
    }
    bid -= NPAIR;
    if (bid < NB_TAB) {
        d_htab(bid, tid, (float*)sm, Wf1, bf1, Wf2, bf2, Htab);
        return;
    }
    bid -= NB_TAB;

    // ---- count + scatter fused (no scan dependency) ----
    int* hist = (int*)sm;                 // [NPAIR]
    int* gbase = hist + NPAIR;            // [NPAIR]
    if (tid < NPAIR) hist[tid] = 0;
    __syncthreads();
    int base = bid * SCHUNK;
    int dv[2], sv[2], pv[2], rn[2], rp[2];
#pragma unroll
    for (int i = 0; i < 2; ++i) {
        int e = base + tid + i * 256;
        if (e < E) {
            dv[i] = edst[e];
            sv[i] = esrc[e];
            pv[i] = Aarr[sv[i]] * 10 + Aarr[dv[i]];
            rn[i] = atomicAdd(&nodecnt[dv[i]], 1);    // rank within node
            rp[i] = atomicAdd(&hist[pv[i]], 1);       // rank within (block,pair)
        }
    }
    __syncthreads();
    if (tid < NPAIR && hist[tid] > 0) gbase[tid] = atomicAdd(&pcur[tid], hist[tid]);
    __syncthreads();
#pragma unroll
    for (int i = 0; i < 2; ++i) {
        int e = base + tid + i * 256;
        if (e < E) {
            int d = dv[i], src = sv[i], p = pv[i];
            int prank = gbase[p] + rp[i];
            if (rn[i] < NCAP && prank < PCAP) {       // impossible overflow guard
                int slot = p * PCAP + prank;
                int ci = (d << 6) + rn[i];
                einv[slot] = ci;
                int b = batch[src];
                float s0 = edge_shifts[e * 3 + 0];
                float s1 = edge_shifts[e * 3 + 1];
                float s2 = edge_shifts[e * 3 + 2];
                const float* cm = cell + b * 9;
                float ev0 = pos[d * 3 + 0] - pos[src * 3 + 0] + s0 * cm[0] + s1 * cm[3] + s2 * cm[6];
                float ev1 = pos[d * 3 + 1] - pos[src * 3 + 1] + s0 * cm[1] + s1 * cm[4] + s2 * cm[7];
                float ev2 = pos[d * 3 + 2] - pos[src * 3 + 2] + s0 * cm[2] + s1 * cm[5] + s2 * cm[8];
                float len = sqrtf(ev0 * ev0 + ev1 * ev1 + ev2 * ev2);
                float inv = 1.0f / (len + 1e-12f);
                reinterpret_cast<float4*>(v4)[ci] =
                    make_float4(ev0 * inv, ev1 * inv, ev2 * inv, len);
                geo[slot] = len * LSCALE;
            }
        }
    }
}

// ================= fused per-edge kernel (static pair id, cnt-based act) =================

__global__ __launch_bounds__(256, 6) void k_edge(
    const int* __restrict__ pcur,
    const int* __restrict__ einv, const float* __restrict__ geo,
    const float* __restrict__ Htab,
    const float* __restrict__ M, const float* __restrict__ bM,
    float* __restrict__ gout)
{
    __shared__ float hbuf[64 * 64];  // 16 KB, [k][lane]
    int bid = blockIdx.x;
    int tid = threadIdx.x;
    int lane = tid & 63;
    int p = __builtin_amdgcn_readfirstlane(bid >> 5);   // PCAP/64 = 32 blocks/pair
    int cnt = min(pcur[p], PCAP);                       // wave-uniform s_load
    int pbase = (bid & 31) * 64;
    if (pbase >= cnt) return;                           // uniform: all 4 waves agree
    int w = __builtin_amdgcn_readfirstlane(tid >> 6);
    int slot = bid * 64 + lane;                         // = p*PCAP + pbase + lane
    bool act = (pbase + lane) < cnt;
    int ci = einv[slot];                                // garbage when !act (guarded)

    // ---- fill hbuf via table gather + linear interp (wave w fills k in [w*16,+16)) ----
    float u = geo[slot];                       // len*LSCALE (garbage in padding: contained)
    int i0 = (int)u;
    i0 = min(max(i0, 0), TS - 2);
    float frac = u - (float)i0;
    const float4* r0 = reinterpret_cast<const float4*>(Htab + (size_t)i0 * 64 + w * 16);
    float4 ta[4], tb[4];
#pragma unroll
    for (int i = 0; i < 4; ++i) { ta[i] = r0[i]; tb[i] = r0[i + 16]; }  // +16 f4 = next row
    float* hb = hbuf + (w * 16) * 64 + lane;
#pragma unroll
    for (int i = 0; i < 4; ++i) {
        hb[(4 * i + 0) * 64] = fmaf(frac, tb[i].x - ta[i].x, ta[i].x);
        hb[(4 * i + 1) * 64] = fmaf(frac, tb[i].y - ta[i].y, ta[i].y);
        hb[(4 * i + 2) * 64] = fmaf(frac, tb[i].z - ta[i].z, ta[i].z);
        hb[(4 * i + 3) * 64] = fmaf(frac, tb[i].w - ta[i].w, ta[i].w);
    }
    __syncthreads();

    // ---- final slice: g[j in w*12..+12) = bM + h @ M  (M wave-uniform s_load) ----
    float g[12];
    {
        const float* bq = bM + p * 48 + w * 12;
#pragma unroll
        for (int j = 0; j < 12; ++j) g[j] = bq[j];
    }
    const float* __restrict__ mp = M + p * 3072 + w * 12;
#pragma unroll 8
    for (int h = 0; h < 64; ++h) {
        float hv = hbuf[h * 64 + lane];
        const float* wr = mp + h * 48;
#pragma unroll
        for (int j = 0; j < 12; ++j) g[j] = fmaf(hv, wr[j], g[j]);
    }

    if (act) {
        float4* gp = reinterpret_cast<float4*>(gout + (size_t)ci * 48 + w * 12);
#pragma unroll
        for (int i = 0; i < 3; ++i)
            gp[i] = make_float4(g[4 * i], g[4 * i + 1], g[4 * i + 2], g[4 * i + 3]);
    }
}

// ================= per-node aggregation (fixed-cap CSR) =================

__global__ __launch_bounds__(256) void k_node(
    const int* __restrict__ nodecnt,
    const float* __restrict__ v4, const float* __restrict__ g,
    int N, float* __restrict__ out)
{
    int tid = threadIdx.x;
    int lane = tid & 63;
    int grp = lane >> 4;
    int o = lane & 15;
    int n = blockIdx.x * 4 + (tid >> 6);
    if (n >= N) return;
    int beg = n << 6;
    int deg = min(nodecnt[n], NCAP);
    int end = beg + deg;
    float a0 = 0.0f;
    float a1[3] = {0.0f, 0.0f, 0.0f};
    float a2[9] = {0.0f, 0.0f, 0.0f, 0.0f, 0.0f, 0.0f, 0.0f, 0.0f, 0.0f};
    for (int k = beg + grp; k < end; k += 4) {
        const float* ge = g + (size_t)k * 48;
        float g0 = ge[o];
        float g1 = ge[16 + o];
        float g2 = ge[32 + o];
        float4 vv = reinterpret_cast<const float4*>(v4)[k];
        float v[3] = {vv.x, vv.y, vv.z};
        a0 += g0;
#pragma unroll
        for (int d = 0; d < 3; ++d) a1[d] = fmaf(g1, v[d], a1[d]);
#pragma unroll
        for (int d1 = 0; d1 < 3; ++d1) {
            float gv = g2 * v[d1];
#pragma unroll
            for (int d2 = 0; d2 < 3; ++d2)
                a2[d1 * 3 + d2] = fmaf(gv, v[d2], a2[d1 * 3 + d2]);
        }
    }
#pragma unroll
    for (int m = 16; m <= 32; m <<= 1) {
        a0 += __shfl_xor(a0, m, 64);
#pragma unroll
        for (int d = 0; d < 3; ++d) a1[d] += __shfl_xor(a1[d], m, 64);
#pragma unroll
        for (int dd = 0; dd < 9; ++dd) a2[dd] += __shfl_xor(a2[dd], m, 64);
    }
    float cnt = (float)deg;
    float invc = (cnt > 0.0f) ? (1.0f / cnt) : 1.0f;
    float* on = out + (size_t)n * 416;
    if (lane < 52)
        reinterpret_cast<float4*>(on + 208)[lane] = make_float4(0.f, 0.f, 0.f, 0.f);
    if (grp == 0) {
        on[o] = a0 * invc;
#pragma unroll
        for (int d = 0; d < 3; ++d) on[16 + o * 3 + d] = a1[d] * invc;
#pragma unroll
        for (int dd = 0; dd < 9; ++dd) on[64 + o * 9 + dd] = a2[dd] * invc;
    }
}

extern "C" void kernel_launch(void* const* d_in, const int* in_sizes, int n_in,
                              void* d_out, int out_size, void* d_ws, size_t ws_size,
                              hipStream_t stream)
{
    const float* pos         = (const float*)d_in[0];
    const float* edge_shifts = (const float*)d_in[1];
    const float* cell        = (const float*)d_in[2];
    const int*   Aarr        = (const int*)d_in[3];
    const int*   batch       = (const int*)d_in[4];
    const int*   esrc        = (const int*)d_in[5];
    const int*   edst        = (const int*)d_in[6];
    const float* emb_table   = (const float*)d_in[7];
    const float* Wa1         = (const float*)d_in[8];
    const float* ba1         = (const float*)d_in[9];
    const float* Wa2         = (const float*)d_in[10];
    const float* ba2         = (const float*)d_in[11];
    const float* Wf1         = (const float*)d_in[12];
    const float* bf1         = (const float*)d_in[13];
    const float* Wf2         = (const float*)d_in[14];
    const float* bf2         = (const float*)d_in[15];
    const float* Wf3         = (const float*)d_in[16];
    const float* bf3         = (const float*)d_in[17];

    int N = in_sizes[0] / 3;
    int E = in_sizes[5];
    int nhblk = (E + SCHUNK - 1) / SCHUNK;
    float* out = (float*)d_out;

    char* ws = (char*)d_ws;
    size_t off = 0;
    auto alloc = [&](size_t bytes) -> void* {
        void* p = ws + off;
        off += (bytes + 255) & ~(size_t)255;
        return p;
    };
    float* M       = (float*)alloc((size_t)NPAIR * 3072 * sizeof(float));
    float* bM      = (float*)alloc((size_t)NPAIR * 48 * sizeof(float));
    float* Htab    = (float*)alloc((size_t)TS * 64 * sizeof(float));
    // --- contiguous zero-init span: nodecnt | pcur (40.6 KB) ---
    int*   nodecnt = (int*)alloc((size_t)N * sizeof(int));
    int*   pcur    = (int*)alloc((size_t)NPAIR * sizeof(int));
    // --- uninitialized ---
    int*   einv    = (int*)alloc((size_t)NSLOT * sizeof(int));
    float* geo     = (float*)alloc((size_t)NSLOT * sizeof(float));
    float* v4      = (float*)alloc((size_t)N * NCAP * 4 * sizeof(float));
    float* g       = (float*)alloc((size_t)N * NCAP * 48 * sizeof(float));
    int nzero = (int)(((char*)pcur + NPAIR * sizeof(int) - (char*)nodecnt) / sizeof(int));
    (void)ws_size; (void)n_in; (void)out_size;

    k_zero<<<(nzero + 255) / 256, 256, 0, stream>>>(nodecnt, nzero);
    k_front<<<NPAIR + NB_TAB + nhblk, 256, 0, stream>>>(
        E, esrc, edst, Aarr, pos, edge_shifts, cell, batch,
        nodecnt, pcur, einv, geo, v4,
        emb_table, Wa1, ba1, Wa2, ba2, Wf1, bf1, Wf2, bf2, Wf3, bf3,
        M, bM, Htab);
    k_edge<<<NPAIR * (PCAP / 64), 256, 0, stream>>>(pcur, einv, geo, Htab, M, bM, g);
    k_node<<<(N + 3) / 4, 256, 0, stream>>>(nodecnt, v4, g, N, out);
}